// Round 1
// 328.240 us; speedup vs baseline: 1.0770x; 1.0770x over previous
//
#include <hip/hip_runtime.h>

// FwFM, single fused kernel, wave-per-sample:
//   out[b] = w0 + sum_f bias[x_bf] + sum_{i<j} Ps[i,j] * <e_i, e_j>
// Ps = 0.5*(W + W^T) strict upper triangle, packed j-major (tri(j)=j(j-1)/2)
// into 741 floats in LDS, computed cooperatively per block from the L2-hot
// 6 KB W matrix (replaces the separate prep_w launch + d_ws round-trip).
// After full unroll every Ps access is a compile-time constant offset ->
// broadcast (conflict-free) ds_read_b128 streams.
//
// Bias is gathered on the VECTOR path (lanes 0..38, one global_load) instead
// of 39 wave-uniform s_loads: scalar loads return out-of-order so the compiler
// must lgkmcnt(0) before any use, which also drained the P streams and stalled
// the FMA chain on cold bias misses. Vector-path bias is tracked by vmcnt and
// folds into the existing lane reduction for free.
//
// Lane = embedding dim d; lane l holds E[:, l] via 39 fully-coalesced 256B row
// loads (the gather IS the transpose). Indices stay wave-uniform (SGPRs) so
// gathers use the scalar-base + lane*4 addressing form (zero VALU per load).

constexpr int NF = 39;
constexpr int D  = 64;
constexpr int NPAIR = NF * (NF - 1) / 2;   // 741
constexpr int WAVES_PER_BLOCK = 4;
constexpr int NT = 64 * WAVES_PER_BLOCK;

__global__ __launch_bounds__(NT) void fwfm_kernel(
    const int*   __restrict__ x,     // (B, 39)
    const float* __restrict__ emb,   // (1e6, 64)
    const float* __restrict__ bias,  // (1e6, 1)
    const float* __restrict__ W,     // (39, 39)
    const float* __restrict__ w0,    // (1,)
    float*       __restrict__ out)   // (B,)
{
    __shared__ float Pl[NPAIR];

    // --- cooperative symmetrized-packed W prep (3 pairs/thread max) ---
    for (int t = threadIdx.x; t < NPAIR; t += NT) {
        // invert tri(j) = j(j-1)/2 <= t
        int j = (int)((1.0f + sqrtf(1.0f + 8.0f * (float)t)) * 0.5f);
        while (j > 1 && j * (j - 1) / 2 > t) --j;
        while ((j + 1) * j / 2 <= t) ++j;
        int i = t - j * (j - 1) / 2;           // i < j
        Pl[t] = 0.5f * (W[i * NF + j] + W[j * NF + i]);
    }

    // Barrier BEFORE any gathers are issued: its mandatory vmcnt(0)/lgkmcnt(0)
    // drain only covers the tiny W reads above, never the embedding gathers.
    __syncthreads();

    const int lane = threadIdx.x & 63;
    const int wave = __builtin_amdgcn_readfirstlane((int)(threadIdx.x >> 6));
    const int b    = blockIdx.x * WAVES_PER_BLOCK + wave;

    const int* xrow = x + (size_t)b * NF;

    // Bias via vector path: lanes 0..38 gather one value each (single
    // global_load, vmcnt-tracked), summed later in the lane reduction.
    float bv = 0.0f;
    if (lane < NF) bv = bias[xrow[lane]];

    // Field indices: wave-uniform -> SGPRs (s_load), enables saddr gathers.
    int idx[NF];
    #pragma unroll
    for (int f = 0; f < NF; ++f) idx[f] = xrow[f];

    // 39 independent, fully-coalesced 256B row loads (1 float/lane).
    float E[NF];
    #pragma unroll
    for (int f = 0; f < NF; ++f)
        E[f] = emb[(size_t)idx[f] * D + lane];

    // Triangular weighted pair-sum: q = sum_j E_j * sum_{i<j} Pl[tri(j)+i]*E_i.
    // Pl reads are broadcast (same address all lanes -> conflict-free) at
    // compile-time consecutive offsets -> compiler merges to ds_read_b128.
    float q = 0.0f;
    #pragma unroll
    for (int j = 1; j < NF; ++j) {
        const int base = j * (j - 1) / 2;  // compile-time after unroll
        float s0 = 0.0f, s1 = 0.0f;
        #pragma unroll
        for (int i = 0; i + 1 < j; i += 2) {
            s0 = fmaf(Pl[base + i],     E[i],     s0);
            s1 = fmaf(Pl[base + i + 1], E[i + 1], s1);
        }
        if (j & 1) s0 = fmaf(Pl[base + j - 1], E[j - 1], s0);
        q = fmaf(E[j], s0 + s1, q);
    }

    // Wave reduction over lanes: sums q over d AND bv over fields in one pass.
    float v = q + bv;
    #pragma unroll
    for (int off = 32; off > 0; off >>= 1)
        v += __shfl_down(v, off, 64);

    if (lane == 0)
        out[b] = w0[0] + v;
}

extern "C" void kernel_launch(void* const* d_in, const int* in_sizes, int n_in,
                              void* d_out, int out_size, void* d_ws, size_t ws_size,
                              hipStream_t stream) {
    const int*   x    = (const int*)d_in[0];
    const float* emb  = (const float*)d_in[1];
    const float* bias = (const float*)d_in[2];
    const float* W    = (const float*)d_in[3];
    const float* w0   = (const float*)d_in[4];
    float*       out  = (float*)d_out;
    (void)d_ws; (void)ws_size;

    const int batch = out_size;  // 16384
    fwfm_kernel<<<batch / WAVES_PER_BLOCK, NT, 0, stream>>>(x, emb, bias, W, w0, out);
}